// Round 21
// baseline (86.341 us; speedup 1.0000x reference)
//
#include <hip/hip_runtime.h>

// CRF log-likelihood, MI355X. SEQ=512, B=1024, T=48.
// SEQUENCE-PARALLEL x8 with 128-THREAD BLOCKS (2 waves/block):
// CDNA caps resident workgroups at 16/CU; 64-thread blocks therefore pin at
// 16 waves/CU = 4 waves/SIMD (R17-R20 all measured ~53% occupancy). 2
// waves/block x 16 blocks/CU = 32 waves/CU = 8 waves/SIMD. Each wave owns
// one chain: cid = blockIdx*2 + wid; b = cid&1023, seg = cid>>10; grid 4096.
// 8-step warm-up from uniform state for s>0 (Birkhoff; validated x5).
// LDS 6 KB/block: f16 trans staging (4.6 KB, cooperative) reused after one
// barrier as two per-wave 3 KB emission double-buffers (CH=8).
// launch_bounds(128,4): 128-reg budget -> Epk stays in arch VGPRs (no AGPR
// shuffling / scratch of the tight (64,8) budget). Matvec: packed-f16 dot2
// (24 readlane + 24 v_dot2_f32_f16). Exact power-of-2 renorm per chunk;
// integer log2 bookkeeping; exact log stitch den = sum(Bs - Ws).

constexpr int SEQ = 512, BN = 1024, TT = 48;
constexpr int CH = 8;
#define LOG2E 1.44269504088896340736f
#define LN2   0.69314718055994530942f

typedef _Float16 h16x2 __attribute__((ext_vector_type(2)));

__device__ __forceinline__ float fexp2(float x) { return __builtin_amdgcn_exp2f(x); }
__device__ __forceinline__ float flog2(float x) { return __builtin_amdgcn_logf(x); }
__device__ __forceinline__ float rlane(float v, int i) {
    return __int_as_float(__builtin_amdgcn_readlane(__float_as_int(v), i));
}
__device__ __forceinline__ float dppswap(float v) {  // lane ^= 1
    return __int_as_float(__builtin_amdgcn_mov_dpp(__float_as_int(v), 0xB1, 0xF, 0xF, true));
}
__device__ __forceinline__ float fdot2(int a, int b, float c) {
#if __has_builtin(__builtin_amdgcn_fdot2)
    return __builtin_amdgcn_fdot2(__builtin_bit_cast(h16x2, a),
                                  __builtin_bit_cast(h16x2, b), c, false);
#else
    float r;
    asm("v_dot2_f32_f16 %0, %1, %2, %3" : "=v"(r) : "v"(a), "v"(b), "v"(c));
    return r;
#endif
}

__global__ __launch_bounds__(128, 4) void crf_fwd(
    const float* __restrict__ emis, const int* __restrict__ tags,
    const int* __restrict__ mask, const float* __restrict__ start_t,
    const float* __restrict__ end_t, const float* __restrict__ trans,
    float* __restrict__ ws)
{
    // 6144 B: phase 1 = f16 trans (2304 halfs, 4608 B, cooperative);
    // phase 2 = two per-wave emission dbufs (wid*768 + buf*384 floats)
    __shared__ __align__(16) float smem[1536];

    const int tid  = threadIdx.x;
    const int wid  = tid >> 6;
    const int lane = tid & 63;
    const int cid  = blockIdx.x * 2 + wid;
    const int b    = cid & 1023;
    const int seg  = cid >> 10;                  // 0..7
    const int cstart = seg ? (8 * seg - 1) : 0;  // 1 warm chunk = 8 steps
    const int cend   = 8 * (seg + 1);
    const int wbase  = wid * 768;

    const bool jv = (lane < TT);
    const int jc = jv ? lane : (TT - 1);
    const int l7 = lane & 7;

    // ---- phase 1: f16 trans in LDS (both waves), build Epk in 24 VGPRs ----
    _Float16* lh = (_Float16*)smem;
    for (int i = tid; i < TT * TT; i += 128) lh[i] = (_Float16)trans[i];
    __syncthreads();
    int Epk[24];
#pragma unroll
    for (int k = 0; k < 24; ++k) {
        const float a  = fexp2((float)lh[(2 * k) * TT + jc] * LOG2E);
        const float bb = fexp2((float)lh[(2 * k + 1) * TT + jc] * LOG2E);
        h16x2 hv = { (_Float16)a, (_Float16)bb };
        Epk[k] = __builtin_bit_cast(int, hv);
    }
#pragma unroll
    for (int k = 0; k < 24; ++k)
        asm volatile("" : "+v"(Epk[k]));
    const float st = start_t[jc];
    const float en = end_t[jc];
    __syncthreads();  // both waves' trans reads retired before dbuf overwrite

    // ---- phase 2: per-wave emission double-buffer (CH=8) ----
    int offs[2];
#pragma unroll
    for (int k = 0; k < 2; ++k) {
        const int g = k * 64 + lane;
        const int r = g / 12, j4 = g % 12;
        offs[k] = r * (BN * TT * 4) + j4 * 16;
    }

#define STAGE_CHUNK(cc, buf)                                                   \
    {                                                                          \
        const char* cb = (const char*)emis + ((size_t)(cc) * CH * BN + b) * (TT * 4); \
        __builtin_amdgcn_global_load_lds(                                      \
            (const __attribute__((address_space(1))) void*)(cb + offs[0]),     \
            (__attribute__((address_space(3))) void*)(&smem[wbase + (buf) * 384]), \
            16, 0, 0);                                                         \
        if (lane < 32)                                                         \
            __builtin_amdgcn_global_load_lds(                                  \
                (const __attribute__((address_space(1))) void*)(cb + offs[1]), \
                (__attribute__((address_space(3))) void*)(&smem[wbase + (buf) * 384 + 256]), \
                16, 0, 0);                                                     \
    }

    STAGE_CHUNK(cstart, 0);
    int tgv = tags[(size_t)(cstart * CH + l7) * BN + b];
    int mkv = mask[(size_t)(cstart * CH + l7) * BN + b];

    asm volatile("s_waitcnt vmcnt(0)" ::: "memory");
    __builtin_amdgcn_sched_barrier(0);

    float r, numpart;
    int la, carry_tag;
    if (seg == 0) {
        const int tag0 = tags[b];
        const float e00 = smem[wbase + jc];
        r = jv ? fexp2(fmaf(st + e00, LOG2E, -6.0f)) : 0.0f;
        la = 6;
        numpart = (lane == tag0) ? (st + e00) : 0.f;
        carry_tag = tag0;
    } else {
        r = jv ? 1.0f : 0.0f;   // warm-up init (scale cancels in B - W)
        la = 0;
        numpart = 0.f;
        carry_tag = 0;
    }
    float numtr = 0.f, numem = 0.f, W = 0.f;
    int mcount = 0;

    STAGE_CHUNK(cstart + 1, 1);
    int tgn = tags[(size_t)((cstart + 1) * CH + l7) * BN + b];
    int mkn = mask[(size_t)((cstart + 1) * CH + l7) * BN + b];

    int cur = 0;

#pragma unroll 1
    for (int c = cstart; c < cend; ++c) {
        const int tbase = c * CH;
        const float* ebc = smem + wbase + cur * 384;
        const bool warm = (c < 8 * seg);

        // ---- chunk-parallel numerator + commit word (lanes 0..7) ----
        const int tmv = (lane < 8 && mkv && (tbase + lane) > 0) ? tgv : -1;
        const unsigned long long vmword = __ballot(tmv >= 0);
        int tprev = __shfl_up(tgv, 1, 64);
        if (lane == 0) tprev = carry_tag;
        if (!warm) {
            if (tmv >= 0) {
                numtr += trans[tprev * TT + tgv];   // f32, L1-hot, exact
                numem += ebc[lane * TT + tgv];
            }
            mcount += __popcll(__ballot(lane < 8 && mkv));
        }
        carry_tag = __builtin_amdgcn_readlane(tgv, 7);
        la += 6 * (int)__popcll(vmword);

        const unsigned gm = (unsigned)vmword & 0xFFu;
        {   // renorm: exact power-of-2 from lane 0's exponent (per 8 steps)
            const float r0 = rlane(r, 0);
            const int m = ((__float_as_int(r0) >> 23) & 0xFF) - 127;
            const float scl = __int_as_float((127 - m) << 23);
            r *= scl;
            la += m;
        }

        // ---- 8 serial steps, loop rolled (register diet) ----
#pragma unroll 1
        for (int u = 0; u < 8; ++u) {
            const float e_t = ebc[u * TT + jc];          // TLP hides LDS latency
            const float emul_u = fexp2(fmaf(e_t, LOG2E, -6.0f));
            const float rx = dppswap(r);
            const int pkw = __builtin_bit_cast(int,
                __builtin_amdgcn_cvt_pkrtz(r, rx));
            float q0 = 0.f, q1 = 0.f, q2 = 0.f, q3 = 0.f;
#pragma unroll
            for (int k = 0; k < 24; k += 4) {
                const int p0 = __builtin_amdgcn_readlane(pkw, 2 * k);
                const int p1 = __builtin_amdgcn_readlane(pkw, 2 * k + 2);
                const int p2 = __builtin_amdgcn_readlane(pkw, 2 * k + 4);
                const int p3 = __builtin_amdgcn_readlane(pkw, 2 * k + 6);
                q0 = fdot2(p0, Epk[k],     q0);
                q1 = fdot2(p1, Epk[k + 1], q1);
                q2 = fdot2(p2, Epk[k + 2], q2);
                q3 = fdot2(p3, Epk[k + 3], q3);
            }
            const float q = (q0 + q1) + (q2 + q3);
            const bool commit = (gm >> u) & 1u;
            r = commit ? (q * emul_u) : r;
        }

        // ---- chunk boundary ----
        asm volatile("s_waitcnt vmcnt(0)" ::: "memory");
        __builtin_amdgcn_sched_barrier(0);
        cur ^= 1;
        tgv = tgn; mkv = mkn;
        if (c + 2 < cend) {
            STAGE_CHUNK(c + 2, cur ^ 1);
            tgn = tags[(size_t)((c + 2) * CH + l7) * BN + b];
            mkn = mask[(size_t)((c + 2) * CH + l7) * BN + b];
        }
        if (seg && c == 8 * seg - 1) {  // warm-up done: capture W (la included)
            float sv = jv ? r : 0.f, se = sv;
#pragma unroll
            for (int d = 1; d < 64; d <<= 1)
                se += __shfl_xor(se, d, 64);
            W = (flog2(se) + (float)la) * LN2;
        }
    }

    // ---- tails (per-wave) ----
    float num = numpart + numtr + numem;
#pragma unroll
    for (int d = 1; d < 64; d <<= 1)
        num += __shfl_xor(num, d, 64);

    float sv = jv ? r : 0.f;
    if (seg == 7) sv = jv ? (r * fexp2(en * LOG2E)) : 0.f;
    float se = sv;
#pragma unroll
    for (int d = 1; d < 64; d <<= 1)
        se += __shfl_xor(se, d, 64);
    const float B = (flog2(se) + (float)la) * LN2;

    if (lane == 0) {
        ws[seg * 1024 + b]           = num;
        ws[8192 + seg * 1024 + b]    = B;
        ws[16384 + seg * 1024 + b]   = W;       // 0 for seg 0
        ws[24576 + seg * 1024 + b]   = (float)mcount;
    }
#undef STAGE_CHUNK
}

__global__ __launch_bounds__(256) void reduce_mean(
    const float* __restrict__ ws, const int* __restrict__ tags,
    const float* __restrict__ end_t, float* __restrict__ out)
{
    const int tid = threadIdx.x;
    float v = 0.f;
#pragma unroll
    for (int k = 0; k < 4; ++k) {
        const int b = tid + 256 * k;
        float num = 0.f, den = 0.f, mcf = 0.f;
#pragma unroll
        for (int s = 0; s < 8; ++s) {
            num += ws[s * 1024 + b];
            den += ws[8192 + s * 1024 + b] - ws[16384 + s * 1024 + b];
            mcf += ws[24576 + s * 1024 + b];
        }
        const int mc = (int)mcf;
        const int lt = tags[(size_t)(mc - 1) * BN + b];
        v += num + end_t[lt] - den;
    }
#pragma unroll
    for (int d = 1; d < 64; d <<= 1)
        v += __shfl_xor(v, d, 64);
    __shared__ float acc[4];
    if ((tid & 63) == 0) acc[tid >> 6] = v;
    __syncthreads();
    if (tid == 0) out[0] = (acc[0] + acc[1] + acc[2] + acc[3]) * (1.f / 1024.f);
}

extern "C" void kernel_launch(void* const* d_in, const int* in_sizes, int n_in,
                              void* d_out, int out_size, void* d_ws, size_t ws_size,
                              hipStream_t stream)
{
    const float* emis    = (const float*)d_in[0];
    const int*   tags    = (const int*)d_in[1];
    const int*   mask    = (const int*)d_in[2];
    const float* start_t = (const float*)d_in[3];
    const float* end_t   = (const float*)d_in[4];
    const float* trans   = (const float*)d_in[5];
    float* ws  = (float*)d_ws;
    float* out = (float*)d_out;

    crf_fwd<<<dim3(4096), dim3(128), 0, stream>>>(emis, tags, mask, start_t, end_t, trans, ws);
    reduce_mean<<<dim3(1), dim3(256), 0, stream>>>(ws, tags, end_t, out);
}

// Round 23
// 66.527 us; speedup vs baseline: 1.2978x; 1.2978x over previous
//
#include <hip/hip_runtime.h>

// CRF log-likelihood, MI355X. SEQ=512, B=1024, T=48.
// SEQUENCE-PARALLEL x8, 128-thread blocks (2 waves/block, grid 4096).
// Matvec broadcast via LDS: even lanes<48 publish packed f16 pair (24 words)
// -> s_waitcnt lgkmcnt(0) + "memory" clobber (FULL IR fence: R22's bug was
// relying on sched_barrier(0), which is IntrNoMem and lets IR passes hoist
// the LDS reads above the predicated store) -> 6 uniform-address
// ds_read_b128 (HW broadcast, conflict-free) -> 24 v_dot2_f32_f16 (builtin-
// gated form, proven R16-R21; R22's raw-asm VOP3P default-modifier semantics
// were unverified). Epk pinned to arch VGPRs inside the chunk loop.
// launch_bounds(128,4): 128-reg budget. 8-step warm-up from uniform state
// for s>0 (Birkhoff; validated x6). Exact power-of-2 renorm per chunk;
// integer log2 bookkeeping; exact log stitch den = sum(Bs - Ws).

constexpr int SEQ = 512, BN = 1024, TT = 48;
constexpr int CH = 8;
#define LOG2E 1.44269504088896340736f
#define LN2   0.69314718055994530942f

typedef int i32x4 __attribute__((ext_vector_type(4)));
typedef _Float16 h16x2 __attribute__((ext_vector_type(2)));

__device__ __forceinline__ float fexp2(float x) { return __builtin_amdgcn_exp2f(x); }
__device__ __forceinline__ float flog2(float x) { return __builtin_amdgcn_logf(x); }
__device__ __forceinline__ float rlane(float v, int i) {
    return __int_as_float(__builtin_amdgcn_readlane(__float_as_int(v), i));
}
__device__ __forceinline__ float dppswap(float v) {  // lane ^= 1
    return __int_as_float(__builtin_amdgcn_mov_dpp(__float_as_int(v), 0xB1, 0xF, 0xF, true));
}
__device__ __forceinline__ float fdot2(int a, int b, float c) {
#if __has_builtin(__builtin_amdgcn_fdot2)
    return __builtin_amdgcn_fdot2(__builtin_bit_cast(h16x2, a),
                                  __builtin_bit_cast(h16x2, b), c, false);
#else
    float r;
    asm("v_dot2_f32_f16 %0, %1, %2, %3" : "=v"(r) : "v"(a), "v"(b), "v"(c));
    return r;
#endif
}

__global__ __launch_bounds__(128, 4) void crf_fwd(
    const float* __restrict__ emis, const int* __restrict__ tags,
    const int* __restrict__ mask, const float* __restrict__ start_t,
    const float* __restrict__ end_t, const float* __restrict__ trans,
    float* __restrict__ ws)
{
    // 6400 B: [0..1535] phase1 f16 trans -> per-wave emission dbufs
    //         [1536..1599] two per-wave 32-int p-broadcast buffers
    __shared__ __align__(16) float smem[1600];

    const int tid  = threadIdx.x;
    const int wid  = tid >> 6;
    const int lane = tid & 63;
    const int cid  = blockIdx.x * 2 + wid;
    const int b    = cid & 1023;
    const int seg  = cid >> 10;                  // 0..7
    const int cstart = seg ? (8 * seg - 1) : 0;  // 1 warm chunk = 8 steps
    const int cend   = 8 * (seg + 1);
    const int wbase  = wid * 768;
    int* pb = (int*)(smem + 1536) + wid * 32;    // 16B-aligned p buffer

    const bool jv = (lane < TT);
    const int jc = jv ? lane : (TT - 1);
    const int l7 = lane & 7;

    // ---- phase 1: f16 trans in LDS (both waves), build Epk in 24 VGPRs ----
    _Float16* lh = (_Float16*)smem;
    for (int i = tid; i < TT * TT; i += 128) lh[i] = (_Float16)trans[i];
    __syncthreads();
    int Epk[24];
#pragma unroll
    for (int k = 0; k < 24; ++k) {
        const float a  = fexp2((float)lh[(2 * k) * TT + jc] * LOG2E);
        const float bb = fexp2((float)lh[(2 * k + 1) * TT + jc] * LOG2E);
        _Float16 h0 = (_Float16)a, h1 = (_Float16)bb;
        Epk[k] = (int)((unsigned)__builtin_bit_cast(unsigned short, h0) |
                       ((unsigned)__builtin_bit_cast(unsigned short, h1) << 16));
    }
#pragma unroll
    for (int k = 0; k < 24; ++k)
        asm volatile("" : "+v"(Epk[k]));
    const float st = start_t[jc];
    const float en = end_t[jc];
    __syncthreads();  // trans reads retired before dbuf overwrite

    // ---- phase 2: per-wave emission double-buffer (CH=8) ----
    int offs[2];
#pragma unroll
    for (int k = 0; k < 2; ++k) {
        const int g = k * 64 + lane;
        const int r = g / 12, j4 = g % 12;
        offs[k] = r * (BN * TT * 4) + j4 * 16;
    }

#define STAGE_CHUNK(cc, buf)                                                   \
    {                                                                          \
        const char* cb = (const char*)emis + ((size_t)(cc) * CH * BN + b) * (TT * 4); \
        __builtin_amdgcn_global_load_lds(                                      \
            (const __attribute__((address_space(1))) void*)(cb + offs[0]),     \
            (__attribute__((address_space(3))) void*)(&smem[wbase + (buf) * 384]), \
            16, 0, 0);                                                         \
        if (lane < 32)                                                         \
            __builtin_amdgcn_global_load_lds(                                  \
                (const __attribute__((address_space(1))) void*)(cb + offs[1]), \
                (__attribute__((address_space(3))) void*)(&smem[wbase + (buf) * 384 + 256]), \
                16, 0, 0);                                                     \
    }

    STAGE_CHUNK(cstart, 0);
    int tgv = tags[(size_t)(cstart * CH + l7) * BN + b];
    int mkv = mask[(size_t)(cstart * CH + l7) * BN + b];

    asm volatile("s_waitcnt vmcnt(0)" ::: "memory");
    __builtin_amdgcn_sched_barrier(0);

    float r, numpart;
    int la, carry_tag;
    if (seg == 0) {
        const int tag0 = tags[b];
        const float e00 = smem[wbase + jc];
        r = jv ? fexp2(fmaf(st + e00, LOG2E, -6.0f)) : 0.0f;
        la = 6;
        numpart = (lane == tag0) ? (st + e00) : 0.f;
        carry_tag = tag0;
    } else {
        r = jv ? 1.0f : 0.0f;   // warm-up init (scale cancels in B - W)
        la = 0;
        numpart = 0.f;
        carry_tag = 0;
    }
    float numtr = 0.f, numem = 0.f, W = 0.f;
    int mcount = 0;

    STAGE_CHUNK(cstart + 1, 1);
    int tgn = tags[(size_t)((cstart + 1) * CH + l7) * BN + b];
    int mkn = mask[(size_t)((cstart + 1) * CH + l7) * BN + b];

    int cur = 0;

#pragma unroll 1
    for (int c = cstart; c < cend; ++c) {
        // pin Epk in arch VGPRs across the loop body (AGPR placement would
        // cost an accvgpr_read per use site)
#pragma unroll
        for (int k = 0; k < 24; ++k)
            asm volatile("" : "+v"(Epk[k]));

        const int tbase = c * CH;
        const float* ebc = smem + wbase + cur * 384;
        const bool warm = (c < 8 * seg);

        // ---- chunk-parallel numerator + commit word (lanes 0..7) ----
        const int tmv = (lane < 8 && mkv && (tbase + lane) > 0) ? tgv : -1;
        const unsigned long long vmword = __ballot(tmv >= 0);
        int tprev = __shfl_up(tgv, 1, 64);
        if (lane == 0) tprev = carry_tag;
        if (!warm) {
            if (tmv >= 0) {
                numtr += trans[tprev * TT + tgv];   // f32, L1-hot, exact
                numem += ebc[lane * TT + tgv];
            }
            mcount += __popcll(__ballot(lane < 8 && mkv));
        }
        carry_tag = __builtin_amdgcn_readlane(tgv, 7);
        la += 6 * (int)__popcll(vmword);

        const unsigned gm = (unsigned)vmword & 0xFFu;
        {   // renorm: exact power-of-2 from lane 0's exponent (per 8 steps)
            const float r0 = rlane(r, 0);
            const int m = ((__float_as_int(r0) >> 23) & 0xFF) - 127;
            const float scl = __int_as_float((127 - m) << 23);
            r *= scl;
            la += m;
        }

        // emission multipliers for this chunk (off the serial chain)
        float emul[8];
#pragma unroll
        for (int u = 0; u < 8; ++u)
            emul[u] = fexp2(fmaf(ebc[u * TT + jc], LOG2E, -6.0f));

        // ---- 8 serial steps (body unrolled: emul static-indexed) ----
#pragma unroll
        for (int u = 0; u < 8; ++u) {
            // pack (r_2k, r_2k+1) on even lanes, publish 24 words to LDS
            const float rx = dppswap(r);
            const int pkw = __builtin_bit_cast(int,
                __builtin_amdgcn_cvt_pkrtz(r, rx));
            if (jv && !(lane & 1)) pb[lane >> 1] = pkw;
            // FULL fence: memory clobber stops IR-level hoisting of the
            // reads over the store; the wait retires the DS write.
            asm volatile("s_waitcnt lgkmcnt(0)" ::: "memory");
            __builtin_amdgcn_sched_barrier(0);
            // 6 uniform-address b128 reads: HW broadcast, conflict-free
            const i32x4* pv = (const i32x4*)pb;
            float q0 = 0.f, q1 = 0.f, q2 = 0.f, q3 = 0.f;
#pragma unroll
            for (int k = 0; k < 6; ++k) {
                const i32x4 w = pv[k];
                q0 = fdot2(w.x, Epk[4 * k],     q0);
                q1 = fdot2(w.y, Epk[4 * k + 1], q1);
                q2 = fdot2(w.z, Epk[4 * k + 2], q2);
                q3 = fdot2(w.w, Epk[4 * k + 3], q3);
            }
            const float q = (q0 + q1) + (q2 + q3);
            const bool commit = (gm >> u) & 1u;
            r = commit ? (q * emul[u]) : r;
        }

        // ---- chunk boundary ----
        asm volatile("s_waitcnt vmcnt(0)" ::: "memory");
        __builtin_amdgcn_sched_barrier(0);
        cur ^= 1;
        tgv = tgn; mkv = mkn;
        if (c + 2 < cend) {
            STAGE_CHUNK(c + 2, cur ^ 1);
            tgn = tags[(size_t)((c + 2) * CH + l7) * BN + b];
            mkn = mask[(size_t)((c + 2) * CH + l7) * BN + b];
        }
        if (seg && c == 8 * seg - 1) {  // warm-up done: capture W (la included)
            float sv = jv ? r : 0.f, se = sv;
#pragma unroll
            for (int d = 1; d < 64; d <<= 1)
                se += __shfl_xor(se, d, 64);
            W = (flog2(se) + (float)la) * LN2;
        }
    }

    // ---- tails (per-wave) ----
    float num = numpart + numtr + numem;
#pragma unroll
    for (int d = 1; d < 64; d <<= 1)
        num += __shfl_xor(num, d, 64);

    float sv = jv ? r : 0.f;
    if (seg == 7) sv = jv ? (r * fexp2(en * LOG2E)) : 0.f;
    float se = sv;
#pragma unroll
    for (int d = 1; d < 64; d <<= 1)
        se += __shfl_xor(se, d, 64);
    const float B = (flog2(se) + (float)la) * LN2;

    if (lane == 0) {
        ws[seg * 1024 + b]           = num;
        ws[8192 + seg * 1024 + b]    = B;
        ws[16384 + seg * 1024 + b]   = W;       // 0 for seg 0
        ws[24576 + seg * 1024 + b]   = (float)mcount;
    }
#undef STAGE_CHUNK
}

__global__ __launch_bounds__(256) void reduce_mean(
    const float* __restrict__ ws, const int* __restrict__ tags,
    const float* __restrict__ end_t, float* __restrict__ out)
{
    const int tid = threadIdx.x;
    float v = 0.f;
#pragma unroll
    for (int k = 0; k < 4; ++k) {
        const int b = tid + 256 * k;
        float num = 0.f, den = 0.f, mcf = 0.f;
#pragma unroll
        for (int s = 0; s < 8; ++s) {
            num += ws[s * 1024 + b];
            den += ws[8192 + s * 1024 + b] - ws[16384 + s * 1024 + b];
            mcf += ws[24576 + s * 1024 + b];
        }
        const int mc = (int)mcf;
        const int lt = tags[(size_t)(mc - 1) * BN + b];
        v += num + end_t[lt] - den;
    }
#pragma unroll
    for (int d = 1; d < 64; d <<= 1)
        v += __shfl_xor(v, d, 64);
    __shared__ float acc[4];
    if ((tid & 63) == 0) acc[tid >> 6] = v;
    __syncthreads();
    if (tid == 0) out[0] = (acc[0] + acc[1] + acc[2] + acc[3]) * (1.f / 1024.f);
}

extern "C" void kernel_launch(void* const* d_in, const int* in_sizes, int n_in,
                              void* d_out, int out_size, void* d_ws, size_t ws_size,
                              hipStream_t stream)
{
    const float* emis    = (const float*)d_in[0];
    const int*   tags    = (const int*)d_in[1];
    const int*   mask    = (const int*)d_in[2];
    const float* start_t = (const float*)d_in[3];
    const float* end_t   = (const float*)d_in[4];
    const float* trans   = (const float*)d_in[5];
    float* ws  = (float*)d_ws;
    float* out = (float*)d_out;

    crf_fwd<<<dim3(4096), dim3(128), 0, stream>>>(emis, tags, mask, start_t, end_t, trans, ws);
    reduce_mean<<<dim3(1), dim3(256), 0, stream>>>(ws, tags, end_t, out);
}

// Round 24
// 64.970 us; speedup vs baseline: 1.3289x; 1.0240x over previous
//
#include <hip/hip_runtime.h>

// CRF log-likelihood, MI355X. SEQ=512, B=1024, T=48.
// SEQUENCE-PARALLEL x8, 128-thread blocks (2 waves/block, grid 4096).
// Matvec broadcast via LDS: even lanes<48 publish packed f16 pair (24 words)
// -> COMPILE-TIME memory fence only (asm volatile "" ::: "memory"): same-wave
// DS ops execute in order (R9/R23-verified), so the write->read RAW needs no
// s_waitcnt; R22's bug was IR-level hoisting of reads above the predicated
// store, which the clobber alone prevents. R23 paid a full synchronous
// lgkmcnt(0) drain per step (~60-120 cyc x 576 wave-steps/SIMD) - removed.
// -> 6 uniform-address ds_read_b128 (HW broadcast, conflict-free) -> 24
// v_dot2_f32_f16 (builtin-gated). Epk pinned to arch VGPRs per chunk.
// launch_bounds(128,4). 8-step warm-up from uniform state for s>0 (Birkhoff;
// validated x7). Exact power-of-2 renorm per chunk; integer log2 bookkeeping;
// exact log stitch den = sum(Bs - Ws). Numerator chunk-parallel.

constexpr int SEQ = 512, BN = 1024, TT = 48;
constexpr int CH = 8;
#define LOG2E 1.44269504088896340736f
#define LN2   0.69314718055994530942f

typedef int i32x4 __attribute__((ext_vector_type(4)));
typedef _Float16 h16x2 __attribute__((ext_vector_type(2)));

__device__ __forceinline__ float fexp2(float x) { return __builtin_amdgcn_exp2f(x); }
__device__ __forceinline__ float flog2(float x) { return __builtin_amdgcn_logf(x); }
__device__ __forceinline__ float rlane(float v, int i) {
    return __int_as_float(__builtin_amdgcn_readlane(__float_as_int(v), i));
}
__device__ __forceinline__ float dppswap(float v) {  // lane ^= 1
    return __int_as_float(__builtin_amdgcn_mov_dpp(__float_as_int(v), 0xB1, 0xF, 0xF, true));
}
__device__ __forceinline__ float fdot2(int a, int b, float c) {
#if __has_builtin(__builtin_amdgcn_fdot2)
    return __builtin_amdgcn_fdot2(__builtin_bit_cast(h16x2, a),
                                  __builtin_bit_cast(h16x2, b), c, false);
#else
    float r;
    asm("v_dot2_f32_f16 %0, %1, %2, %3" : "=v"(r) : "v"(a), "v"(b), "v"(c));
    return r;
#endif
}

__global__ __launch_bounds__(128, 4) void crf_fwd(
    const float* __restrict__ emis, const int* __restrict__ tags,
    const int* __restrict__ mask, const float* __restrict__ start_t,
    const float* __restrict__ end_t, const float* __restrict__ trans,
    float* __restrict__ ws)
{
    // 6400 B: [0..1535] phase1 f16 trans -> per-wave emission dbufs
    //         [1536..1599] two per-wave 32-int p-broadcast buffers
    __shared__ __align__(16) float smem[1600];

    const int tid  = threadIdx.x;
    const int wid  = tid >> 6;
    const int lane = tid & 63;
    const int cid  = blockIdx.x * 2 + wid;
    const int b    = cid & 1023;
    const int seg  = cid >> 10;                  // 0..7
    const int cstart = seg ? (8 * seg - 1) : 0;  // 1 warm chunk = 8 steps
    const int cend   = 8 * (seg + 1);
    const int wbase  = wid * 768;
    int* pb = (int*)(smem + 1536) + wid * 32;    // 16B-aligned p buffer

    const bool jv = (lane < TT);
    const int jc = jv ? lane : (TT - 1);
    const int l7 = lane & 7;

    // ---- phase 1: f16 trans in LDS (both waves), build Epk in 24 VGPRs ----
    _Float16* lh = (_Float16*)smem;
    for (int i = tid; i < TT * TT; i += 128) lh[i] = (_Float16)trans[i];
    __syncthreads();
    int Epk[24];
#pragma unroll
    for (int k = 0; k < 24; ++k) {
        const float a  = fexp2((float)lh[(2 * k) * TT + jc] * LOG2E);
        const float bb = fexp2((float)lh[(2 * k + 1) * TT + jc] * LOG2E);
        _Float16 h0 = (_Float16)a, h1 = (_Float16)bb;
        Epk[k] = (int)((unsigned)__builtin_bit_cast(unsigned short, h0) |
                       ((unsigned)__builtin_bit_cast(unsigned short, h1) << 16));
    }
#pragma unroll
    for (int k = 0; k < 24; ++k)
        asm volatile("" : "+v"(Epk[k]));
    const float st = start_t[jc];
    const float en = end_t[jc];
    __syncthreads();  // trans reads retired before dbuf overwrite

    // ---- phase 2: per-wave emission double-buffer (CH=8) ----
    int offs[2];
#pragma unroll
    for (int k = 0; k < 2; ++k) {
        const int g = k * 64 + lane;
        const int r = g / 12, j4 = g % 12;
        offs[k] = r * (BN * TT * 4) + j4 * 16;
    }

#define STAGE_CHUNK(cc, buf)                                                   \
    {                                                                          \
        const char* cb = (const char*)emis + ((size_t)(cc) * CH * BN + b) * (TT * 4); \
        __builtin_amdgcn_global_load_lds(                                      \
            (const __attribute__((address_space(1))) void*)(cb + offs[0]),     \
            (__attribute__((address_space(3))) void*)(&smem[wbase + (buf) * 384]), \
            16, 0, 0);                                                         \
        if (lane < 32)                                                         \
            __builtin_amdgcn_global_load_lds(                                  \
                (const __attribute__((address_space(1))) void*)(cb + offs[1]), \
                (__attribute__((address_space(3))) void*)(&smem[wbase + (buf) * 384 + 256]), \
                16, 0, 0);                                                     \
    }

    STAGE_CHUNK(cstart, 0);
    int tgv = tags[(size_t)(cstart * CH + l7) * BN + b];
    int mkv = mask[(size_t)(cstart * CH + l7) * BN + b];

    asm volatile("s_waitcnt vmcnt(0)" ::: "memory");
    __builtin_amdgcn_sched_barrier(0);

    float r, numpart;
    int la, carry_tag;
    if (seg == 0) {
        const int tag0 = tags[b];
        const float e00 = smem[wbase + jc];
        r = jv ? fexp2(fmaf(st + e00, LOG2E, -6.0f)) : 0.0f;
        la = 6;
        numpart = (lane == tag0) ? (st + e00) : 0.f;
        carry_tag = tag0;
    } else {
        r = jv ? 1.0f : 0.0f;   // warm-up init (scale cancels in B - W)
        la = 0;
        numpart = 0.f;
        carry_tag = 0;
    }
    float numtr = 0.f, numem = 0.f, W = 0.f;
    int mcount = 0;

    STAGE_CHUNK(cstart + 1, 1);
    int tgn = tags[(size_t)((cstart + 1) * CH + l7) * BN + b];
    int mkn = mask[(size_t)((cstart + 1) * CH + l7) * BN + b];

    int cur = 0;

#pragma unroll 1
    for (int c = cstart; c < cend; ++c) {
        // pin Epk in arch VGPRs across the loop body
#pragma unroll
        for (int k = 0; k < 24; ++k)
            asm volatile("" : "+v"(Epk[k]));

        const int tbase = c * CH;
        const float* ebc = smem + wbase + cur * 384;
        const bool warm = (c < 8 * seg);

        // ---- chunk-parallel numerator + commit word (lanes 0..7) ----
        const int tmv = (lane < 8 && mkv && (tbase + lane) > 0) ? tgv : -1;
        const unsigned long long vmword = __ballot(tmv >= 0);
        int tprev = __shfl_up(tgv, 1, 64);
        if (lane == 0) tprev = carry_tag;
        if (!warm) {
            if (tmv >= 0) {
                numtr += trans[tprev * TT + tgv];   // f32, L1-hot, exact
                numem += ebc[lane * TT + tgv];
            }
            mcount += __popcll(__ballot(lane < 8 && mkv));
        }
        carry_tag = __builtin_amdgcn_readlane(tgv, 7);
        la += 6 * (int)__popcll(vmword);

        const unsigned gm = (unsigned)vmword & 0xFFu;
        {   // renorm: exact power-of-2 from lane 0's exponent (per 8 steps)
            const float r0 = rlane(r, 0);
            const int m = ((__float_as_int(r0) >> 23) & 0xFF) - 127;
            const float scl = __int_as_float((127 - m) << 23);
            r *= scl;
            la += m;
        }

        // emission multipliers for this chunk (off the serial chain)
        float emul[8];
#pragma unroll
        for (int u = 0; u < 8; ++u)
            emul[u] = fexp2(fmaf(ebc[u * TT + jc], LOG2E, -6.0f));

        // ---- 8 serial steps (body unrolled: emul static-indexed) ----
#pragma unroll
        for (int u = 0; u < 8; ++u) {
            // pack (r_2k, r_2k+1) on even lanes, publish 24 words to LDS
            const float rx = dppswap(r);
            const int pkw = __builtin_bit_cast(int,
                __builtin_amdgcn_cvt_pkrtz(r, rx));
            if (jv && !(lane & 1)) pb[lane >> 1] = pkw;
            // compile-time fence ONLY: blocks IR hoisting of the reads over
            // the store; same-wave DS ops are HW in-order, and the read->use
            // dependency gets the compiler's own counted lgkmcnt.
            asm volatile("" ::: "memory");
            // 6 uniform-address b128 reads: HW broadcast, conflict-free
            const i32x4* pv = (const i32x4*)pb;
            float q0 = 0.f, q1 = 0.f, q2 = 0.f, q3 = 0.f;
#pragma unroll
            for (int k = 0; k < 6; ++k) {
                const i32x4 w = pv[k];
                q0 = fdot2(w.x, Epk[4 * k],     q0);
                q1 = fdot2(w.y, Epk[4 * k + 1], q1);
                q2 = fdot2(w.z, Epk[4 * k + 2], q2);
                q3 = fdot2(w.w, Epk[4 * k + 3], q3);
            }
            const float q = (q0 + q1) + (q2 + q3);
            const bool commit = (gm >> u) & 1u;
            r = commit ? (q * emul[u]) : r;
        }

        // ---- chunk boundary ----
        asm volatile("s_waitcnt vmcnt(0)" ::: "memory");
        __builtin_amdgcn_sched_barrier(0);
        cur ^= 1;
        tgv = tgn; mkv = mkn;
        if (c + 2 < cend) {
            STAGE_CHUNK(c + 2, cur ^ 1);
            tgn = tags[(size_t)((c + 2) * CH + l7) * BN + b];
            mkn = mask[(size_t)((c + 2) * CH + l7) * BN + b];
        }
        if (seg && c == 8 * seg - 1) {  // warm-up done: capture W (la included)
            float sv = jv ? r : 0.f, se = sv;
#pragma unroll
            for (int d = 1; d < 64; d <<= 1)
                se += __shfl_xor(se, d, 64);
            W = (flog2(se) + (float)la) * LN2;
        }
    }

    // ---- tails (per-wave) ----
    float num = numpart + numtr + numem;
#pragma unroll
    for (int d = 1; d < 64; d <<= 1)
        num += __shfl_xor(num, d, 64);

    float sv = jv ? r : 0.f;
    if (seg == 7) sv = jv ? (r * fexp2(en * LOG2E)) : 0.f;
    float se = sv;
#pragma unroll
    for (int d = 1; d < 64; d <<= 1)
        se += __shfl_xor(se, d, 64);
    const float B = (flog2(se) + (float)la) * LN2;

    if (lane == 0) {
        ws[seg * 1024 + b]           = num;
        ws[8192 + seg * 1024 + b]    = B;
        ws[16384 + seg * 1024 + b]   = W;       // 0 for seg 0
        ws[24576 + seg * 1024 + b]   = (float)mcount;
    }
#undef STAGE_CHUNK
}

__global__ __launch_bounds__(256) void reduce_mean(
    const float* __restrict__ ws, const int* __restrict__ tags,
    const float* __restrict__ end_t, float* __restrict__ out)
{
    const int tid = threadIdx.x;
    float v = 0.f;
#pragma unroll
    for (int k = 0; k < 4; ++k) {
        const int b = tid + 256 * k;
        float num = 0.f, den = 0.f, mcf = 0.f;
#pragma unroll
        for (int s = 0; s < 8; ++s) {
            num += ws[s * 1024 + b];
            den += ws[8192 + s * 1024 + b] - ws[16384 + s * 1024 + b];
            mcf += ws[24576 + s * 1024 + b];
        }
        const int mc = (int)mcf;
        const int lt = tags[(size_t)(mc - 1) * BN + b];
        v += num + end_t[lt] - den;
    }
#pragma unroll
    for (int d = 1; d < 64; d <<= 1)
        v += __shfl_xor(v, d, 64);
    __shared__ float acc[4];
    if ((tid & 63) == 0) acc[tid >> 6] = v;
    __syncthreads();
    if (tid == 0) out[0] = (acc[0] + acc[1] + acc[2] + acc[3]) * (1.f / 1024.f);
}

extern "C" void kernel_launch(void* const* d_in, const int* in_sizes, int n_in,
                              void* d_out, int out_size, void* d_ws, size_t ws_size,
                              hipStream_t stream)
{
    const float* emis    = (const float*)d_in[0];
    const int*   tags    = (const int*)d_in[1];
    const int*   mask    = (const int*)d_in[2];
    const float* start_t = (const float*)d_in[3];
    const float* end_t   = (const float*)d_in[4];
    const float* trans   = (const float*)d_in[5];
    float* ws  = (float*)d_ws;
    float* out = (float*)d_out;

    crf_fwd<<<dim3(4096), dim3(128), 0, stream>>>(emis, tags, mask, start_t, end_t, trans, ws);
    reduce_mean<<<dim3(1), dim3(256), 0, stream>>>(ws, tags, end_t, out);
}